// Round 9
// baseline (672.261 us; speedup 1.0000x reference)
//
#include <hip/hip_runtime.h>

// GCN 2-layer forward: out = GCNConv(relu(GCNConv(x,W1,b1)),W2,b2), returns (out, x_emb)
// N=100000 nodes, E=6400000 edges, feature dims 16 -> 8 -> 2.
//
// ROUND-5 LAW: device f32 atomics ~20G/s, 32B L2-writethrough each => bucket+LDS.
// ROUND-8 PROFILE: k_gather1 = 271us @ 3.9% HBM, VALU 1.4%, occ 35.6% =>
//   LDS-ATOMIC BOUND: 8 scalar atomics/record at bank (cl*8+k)%32 = 8*(cl%4)
//   => 64 lanes on 4 banks = 16-way conflict (m136: ~5.7x serialization), and
//   64KB LDS capped residency at 2 blocks/CU so gather latency was exposed.
// FIX: (1) 8 lanes co-own a record (k=t&7): 1 atomic/lane, ~2-way conflicts (free),
//      h1s gather becomes 32B-contiguous/record; (2) GSIZE 2000->1000: acc=32KB
//      => 4 blocks/CU, 2x resident waves.
//
//  FAST PATH (ws >= ~87MB): k_detect, k_bucket (100 groups, 312K device atomics),
//   k_deg, k_node1m (h1s = dinv*(x@W1) prescaled), k_gather1 (8-lane records),
//   k_epi1m (merge; xemb = di*(sum+h1s)+b1; h2s = di*relu@W2), k_gather2 (2-lane),
//   k_epi2m. Self-loops analytic: d^2*h == di*hs, folded into merges.
//  FALLBACK (ws too small): round-5 passing atomic-scatter kernels.

#define NN 100000
#define NE 6400000

#define GROUPS 100
#define GSIZE  1000      // NN / GROUPS
#define KCH    6         // chunks (partials) per group -> 600 gather blocks
#define CAP    70000     // per-group capacity (mean 64000, sigma~252 -> +24 sigma)
#define BK     2048      // edges per bucket block
#define NBB    (NE/BK)   // 3125 exactly

// ---------- shared helpers ----------

__device__ __forceinline__ void atomAdd(float* p, float v) {
#if defined(__HIP_DEVICE_COMPILE__)
    unsafeAtomicAdd(p, v);   // native global_atomic_add_f32 (fallback path only)
#else
    atomicAdd(p, v);
#endif
}

__device__ __forceinline__ void load4(const void* __restrict__ ei, int is64, size_t q,
                                      size_t halfoff, int v[4]) {
    if (is64) {
        const longlong2* p = (const longlong2*)((const long long*)ei + halfoff);
        longlong2 a = p[2 * q], b = p[2 * q + 1];
        v[0] = (int)a.x; v[1] = (int)a.y; v[2] = (int)b.x; v[3] = (int)b.y;
    } else {
        int4 t = ((const int4*)((const int*)ei + halfoff))[q];
        v[0] = t.x; v[1] = t.y; v[2] = t.z; v[3] = t.w;
    }
}

__global__ void k_detect(const int* __restrict__ ei32, int* __restrict__ flag) {
    int z = 0;
#pragma unroll
    for (int i = 1; i < 64; i += 2) z |= ei32[i];  // high words if int64
    *flag = (z == 0) ? 1 : 0;
}

// ---------- FAST PATH ----------

__global__ __launch_bounds__(256) void k_bucket(const void* __restrict__ ei,
                                                const float* __restrict__ ew,
                                                const int* __restrict__ flag,
                                                unsigned* __restrict__ cursors,
                                                unsigned long long* __restrict__ buckets) {
    __shared__ int hist[GROUPS];
    __shared__ int base[GROUPS];
    const int is64 = *flag;
    const int t = threadIdx.x;
    if (t < GROUPS) hist[t] = 0;
    __syncthreads();
    const size_t q0 = (size_t)blockIdx.x * (BK / 4);
    // pass 1: count cols per group (chunk stays cache-hot for pass 2)
#pragma unroll
    for (int it = 0; it < BK / 4 / 256; ++it) {  // 2 iters
        size_t q = q0 + (size_t)it * 256 + t;
        int c[4]; load4(ei, is64, q, NE, c);
#pragma unroll
        for (int k = 0; k < 4; ++k) atomicAdd(&hist[c[k] / GSIZE], 1);
    }
    __syncthreads();
    if (t < GROUPS) {
        base[t] = (int)atomicAdd(&cursors[t], (unsigned)hist[t]);  // 100 device atomics/block
        hist[t] = 0;                                               // reuse as intra-block cursor
    }
    __syncthreads();
    // pass 2: place records (per-group streams contiguous within a block)
#pragma unroll
    for (int it = 0; it < BK / 4 / 256; ++it) {
        size_t q = q0 + (size_t)it * 256 + t;
        int r[4], c[4];
        load4(ei, is64, q, 0, r);
        load4(ei, is64, q, NE, c);
        float4 wv = ((const float4*)ew)[q];
        float w[4] = {wv.x, wv.y, wv.z, wv.w};
#pragma unroll
        for (int k = 0; k < 4; ++k) {
            int g = c[k] / GSIZE;
            int cl = c[k] - g * GSIZE;
            int idx = atomicAdd(&hist[g], 1) + base[g];  // LDS atomic
            if (idx < CAP) {
                unsigned pk = (unsigned)r[k] | ((unsigned)cl << 17);
                buckets[(size_t)g * CAP + idx] =
                    (unsigned long long)pk | ((unsigned long long)__float_as_uint(w[k]) << 32);
            }
        }
    }
}

__global__ __launch_bounds__(512) void k_deg(const unsigned* __restrict__ cursors,
                                             const unsigned long long* __restrict__ buckets,
                                             float* __restrict__ degpart) {
    __shared__ float acc[GSIZE];  // 4 KB
    const int t = threadIdx.x;
    const int g = blockIdx.x / KCH, j = blockIdx.x % KCH;
    for (int i = t; i < GSIZE; i += 512) acc[i] = 0.0f;
    __syncthreads();
    unsigned cu = cursors[g];
    const int cnt = (int)(cu < (unsigned)CAP ? cu : (unsigned)CAP);
    const int cpk = (cnt + KCH - 1) / KCH;
    const int lo = j * cpk;
    const int hi = (lo + cpk < cnt) ? lo + cpk : cnt;
    const unsigned long long* B = buckets + (size_t)g * CAP;
    for (int i = lo + t; i < hi; i += 512) {
        unsigned long long rec = B[i];
        int cl = ((unsigned)rec) >> 17;
        float w = __uint_as_float((unsigned)(rec >> 32));
        atomicAdd(&acc[cl], w);  // LDS atomic, random bank, ~2-way expected
    }
    __syncthreads();
    float* dst = degpart + ((size_t)g * KCH + j) * GSIZE;
    for (int i = t; i < GSIZE; i += 512) dst[i] = acc[i];
}

__global__ __launch_bounds__(256) void k_node1m(const float* __restrict__ x,
                                                const float* __restrict__ W1,
                                                const float* __restrict__ degpart,
                                                float* __restrict__ dinv,
                                                float* __restrict__ h1s) {
    __shared__ float sW[128];  // W1 is 16x8
    if (threadIdx.x < 128) sW[threadIdx.x] = W1[threadIdx.x];
    __syncthreads();
    int i = blockIdx.x * blockDim.x + threadIdx.x;
    if (i >= NN) return;
    int g = i / GSIZE, il = i - g * GSIZE;
    float d = 1.0f;  // self-loop weight
#pragma unroll
    for (int j = 0; j < KCH; ++j) d += degpart[((size_t)g * KCH + j) * GSIZE + il];
    float di = rsqrtf(d);
    dinv[i] = di;
    const float4* xp = reinterpret_cast<const float4*>(x + (size_t)i * 16);
    float acc[8];
#pragma unroll
    for (int j = 0; j < 8; ++j) acc[j] = 0.0f;
#pragma unroll
    for (int kq = 0; kq < 4; ++kq) {
        float4 v = xp[kq];
        float vv[4] = {v.x, v.y, v.z, v.w};
#pragma unroll
        for (int kk = 0; kk < 4; ++kk) {
            int k = kq * 4 + kk;
#pragma unroll
            for (int j = 0; j < 8; ++j) acc[j] += vv[kk] * sW[k * 8 + j];
        }
    }
    // store dinv-prescaled features: gather needs NO dinv[r] lookup
    float4* hp = reinterpret_cast<float4*>(h1s + (size_t)i * 8);
    hp[0] = make_float4(di * acc[0], di * acc[1], di * acc[2], di * acc[3]);
    hp[1] = make_float4(di * acc[4], di * acc[5], di * acc[6], di * acc[7]);
}

__global__ __launch_bounds__(512) void k_gather1(const unsigned* __restrict__ cursors,
                                                 const unsigned long long* __restrict__ buckets,
                                                 const float* __restrict__ h1s,
                                                 float* __restrict__ g1part) {
    __shared__ float acc[GSIZE * 8];  // 32000 B -> 4 blocks/CU
    const int t = threadIdx.x;
    const int g = blockIdx.x / KCH, j = blockIdx.x % KCH;
    for (int i = t; i < GSIZE * 8; i += 512) acc[i] = 0.0f;
    __syncthreads();
    unsigned cu = cursors[g];
    const int cnt = (int)(cu < (unsigned)CAP ? cu : (unsigned)CAP);
    const int cpk = (cnt + KCH - 1) / KCH;
    const int lo = j * cpk;
    const int hi = (lo + cpk < cnt) ? lo + cpk : cnt;
    const unsigned long long* B = buckets + (size_t)g * CAP;
    // 8 lanes co-own one record: k = feature lane, rs = record slot.
    // => 1 LDS atomic per lane (was 8), banks cl*8+k: 8 records spread over the
    //    4 octet positions => ~2-way conflict (free, m136). h1s read is 32B
    //    contiguous per record, coalesced across the wave.
    const int k = t & 7;
    const int rs = t >> 3;   // 0..63
    for (int i = lo + rs; i < hi; i += 64) {
        unsigned long long rec = B[i];           // 8 lanes same 8B -> broadcast line
        unsigned pk = (unsigned)rec;
        int r = pk & 0x1FFFF;
        int cl = pk >> 17;
        float w = __uint_as_float((unsigned)(rec >> 32));  // nrm folded into h1s
        float h = h1s[(size_t)r * 8 + k];
        atomicAdd(&acc[cl * 8 + k], w * h);
    }
    __syncthreads();
    float* dst = g1part + ((size_t)g * KCH + j) * (GSIZE * 8);
    for (int i = t; i < GSIZE * 8; i += 512) dst[i] = acc[i];
}

__global__ __launch_bounds__(256) void k_epi1m(const float* __restrict__ g1part,
                                               const float* __restrict__ h1s,
                                               const float* __restrict__ dinv,
                                               const float* __restrict__ W2,  // 8x2
                                               const float* __restrict__ b1,
                                               float* __restrict__ xemb,
                                               float* __restrict__ h2s) {
    int i = blockIdx.x * blockDim.x + threadIdx.x;
    if (i >= NN) return;
    int g = i / GSIZE, il = i - g * GSIZE;
    float s[8];
#pragma unroll
    for (int m = 0; m < 8; ++m) s[m] = 0.0f;
#pragma unroll
    for (int j = 0; j < KCH; ++j) {
        const float4* p = (const float4*)(g1part + (((size_t)g * KCH + j) * GSIZE + il) * 8);
        float4 a = p[0], b = p[1];
        s[0] += a.x; s[1] += a.y; s[2] += a.z; s[3] += a.w;
        s[4] += b.x; s[5] += b.y; s[6] += b.z; s[7] += b.w;
    }
    float di = dinv[i];
    const float4* hp = (const float4*)(h1s + (size_t)i * 8);  // h1s = di * h1_raw
    float4 ha = hp[0], hb = hp[1];
    float hv[8] = {ha.x, ha.y, ha.z, ha.w, hb.x, hb.y, hb.z, hb.w};
    float e[8];
    // e = di*sum + di^2*h1_raw + b1 = di*(sum + h1s) + b1   (exact rewrite)
#pragma unroll
    for (int m = 0; m < 8; ++m) e[m] = di * (s[m] + hv[m]) + b1[m];
    float4* xo = reinterpret_cast<float4*>(xemb + (size_t)i * 8);
    xo[0] = make_float4(e[0], e[1], e[2], e[3]);
    xo[1] = make_float4(e[4], e[5], e[6], e[7]);
    float s0 = 0.0f, s1 = 0.0f;
#pragma unroll
    for (int m = 0; m < 8; ++m) {
        float rr = fmaxf(e[m], 0.0f);
        s0 += rr * W2[m * 2 + 0];
        s1 += rr * W2[m * 2 + 1];
    }
    // store dinv-prescaled layer-2 features
    *reinterpret_cast<float2*>(h2s + (size_t)i * 2) = make_float2(di * s0, di * s1);
}

__global__ __launch_bounds__(512) void k_gather2(const unsigned* __restrict__ cursors,
                                                 const unsigned long long* __restrict__ buckets,
                                                 const float* __restrict__ h2s,
                                                 float* __restrict__ g2part) {
    __shared__ float acc[GSIZE * 2];  // 8000 B
    const int t = threadIdx.x;
    const int g = blockIdx.x / KCH, j = blockIdx.x % KCH;
    for (int i = t; i < GSIZE * 2; i += 512) acc[i] = 0.0f;
    __syncthreads();
    unsigned cu = cursors[g];
    const int cnt = (int)(cu < (unsigned)CAP ? cu : (unsigned)CAP);
    const int cpk = (cnt + KCH - 1) / KCH;
    const int lo = j * cpk;
    const int hi = (lo + cpk < cnt) ? lo + cpk : cnt;
    const unsigned long long* B = buckets + (size_t)g * CAP;
    // 2 lanes per record
    const int k = t & 1;
    const int rs = t >> 1;   // 0..255
    for (int i = lo + rs; i < hi; i += 256) {
        unsigned long long rec = B[i];
        unsigned pk = (unsigned)rec;
        int r = pk & 0x1FFFF;
        int cl = pk >> 17;
        float w = __uint_as_float((unsigned)(rec >> 32));
        float h = h2s[(size_t)r * 2 + k];
        atomicAdd(&acc[cl * 2 + k], w * h);
    }
    __syncthreads();
    float* dst = g2part + ((size_t)g * KCH + j) * (GSIZE * 2);
    for (int i = t; i < GSIZE * 2; i += 512) dst[i] = acc[i];
}

__global__ __launch_bounds__(256) void k_epi2m(const float* __restrict__ g2part,
                                               const float* __restrict__ h2s,
                                               const float* __restrict__ dinv,
                                               const float* __restrict__ b2,
                                               float* __restrict__ out) {
    int i = blockIdx.x * blockDim.x + threadIdx.x;
    if (i >= NN) return;
    int g = i / GSIZE, il = i - g * GSIZE;
    float s0 = 0.0f, s1 = 0.0f;
#pragma unroll
    for (int j = 0; j < KCH; ++j) {
        float2 p = *(const float2*)(g2part + (((size_t)g * KCH + j) * GSIZE + il) * 2);
        s0 += p.x; s1 += p.y;
    }
    float di = dinv[i];
    float2 h = *(const float2*)(h2s + (size_t)i * 2);  // h2s = di * h2_raw
    // out = di*sum + di^2*h2_raw + b2 = di*(sum + h2s) + b2
    *reinterpret_cast<float2*>(out + (size_t)i * 2) =
        make_float2(di * (s0 + h.x) + b2[0], di * (s1 + h.y) + b2[1]);
}

// ---------- FALLBACK (round-5, known-passing) ----------

__global__ __launch_bounds__(256) void k_prep(const void* __restrict__ ei,
                                              const float* __restrict__ ew,
                                              const int* __restrict__ flag,
                                              float* __restrict__ deg) {
    const int is64 = *flag;
    const int stride = gridDim.x * blockDim.x;
    const int nv = NE / 4;
    const float4* ewv = (const float4*)ew;
    for (int v = blockIdx.x * blockDim.x + threadIdx.x; v < nv; v += stride) {
        int c[4]; load4(ei, is64, v, NE, c);
        float4 w = ewv[v];
        atomAdd(&deg[c[0]], w.x);
        atomAdd(&deg[c[1]], w.y);
        atomAdd(&deg[c[2]], w.z);
        atomAdd(&deg[c[3]], w.w);
    }
}

__global__ __launch_bounds__(256) void k_node1(const float* __restrict__ x,
                                               const float* __restrict__ W1,
                                               const float* __restrict__ deg,
                                               float* __restrict__ dinv,
                                               float* __restrict__ h1) {
    __shared__ float sW[128];
    if (threadIdx.x < 128) sW[threadIdx.x] = W1[threadIdx.x];
    __syncthreads();
    int i = blockIdx.x * blockDim.x + threadIdx.x;
    if (i >= NN) return;
    float d = deg[i] + 1.0f;
    dinv[i] = rsqrtf(d);
    const float4* xp = reinterpret_cast<const float4*>(x + (size_t)i * 16);
    float acc[8];
#pragma unroll
    for (int j = 0; j < 8; ++j) acc[j] = 0.0f;
#pragma unroll
    for (int kq = 0; kq < 4; ++kq) {
        float4 v = xp[kq];
        float vv[4] = {v.x, v.y, v.z, v.w};
#pragma unroll
        for (int kk = 0; kk < 4; ++kk) {
            int k = kq * 4 + kk;
#pragma unroll
            for (int j = 0; j < 8; ++j) acc[j] += vv[kk] * sW[k * 8 + j];
        }
    }
    float4* hp = reinterpret_cast<float4*>(h1 + (size_t)i * 8);
    hp[0] = make_float4(acc[0], acc[1], acc[2], acc[3]);
    hp[1] = make_float4(acc[4], acc[5], acc[6], acc[7]);
}

__device__ __forceinline__ void agg1_edge(int r, int c, float w,
                                          const float* __restrict__ dinv,
                                          const float* __restrict__ h1,
                                          float* __restrict__ agg1) {
    float nrm = dinv[r] * w * dinv[c];
    const float4* hp = reinterpret_cast<const float4*>(h1 + (size_t)r * 8);
    float4 a = hp[0];
    float4 b = hp[1];
    float* o = agg1 + (size_t)c * 8;
    atomAdd(o + 0, nrm * a.x);
    atomAdd(o + 1, nrm * a.y);
    atomAdd(o + 2, nrm * a.z);
    atomAdd(o + 3, nrm * a.w);
    atomAdd(o + 4, nrm * b.x);
    atomAdd(o + 5, nrm * b.y);
    atomAdd(o + 6, nrm * b.z);
    atomAdd(o + 7, nrm * b.w);
}

__global__ __launch_bounds__(256) void k_agg1(const void* __restrict__ ei,
                                              const float* __restrict__ ew,
                                              const int* __restrict__ flag,
                                              const float* __restrict__ dinv,
                                              const float* __restrict__ h1,
                                              float* __restrict__ agg1) {
    const int is64 = *flag;
    const int stride = gridDim.x * blockDim.x;
    const int nv = NE / 4;
    const float4* ewv = (const float4*)ew;
    for (int v = blockIdx.x * blockDim.x + threadIdx.x; v < nv; v += stride) {
        int r[4], c[4];
        load4(ei, is64, v, 0, r);
        load4(ei, is64, v, NE, c);
        float4 w = ewv[v];
        agg1_edge(r[0], c[0], w.x, dinv, h1, agg1);
        agg1_edge(r[1], c[1], w.y, dinv, h1, agg1);
        agg1_edge(r[2], c[2], w.z, dinv, h1, agg1);
        agg1_edge(r[3], c[3], w.w, dinv, h1, agg1);
    }
}

__global__ __launch_bounds__(256) void k_epi1(const float* __restrict__ agg1,
                                              const float* __restrict__ h1,
                                              const float* __restrict__ dinv,
                                              const float* __restrict__ W2,
                                              const float* __restrict__ b1,
                                              float* __restrict__ xemb,
                                              float* __restrict__ h2) {
    int i = blockIdx.x * blockDim.x + threadIdx.x;
    if (i >= NN) return;
    float di = dinv[i];
    float d2 = di * di;
    const float4* ap = reinterpret_cast<const float4*>(agg1 + (size_t)i * 8);
    const float4* hp = reinterpret_cast<const float4*>(h1 + (size_t)i * 8);
    float4 a0 = ap[0], a1 = ap[1];
    float4 g0 = hp[0], g1 = hp[1];
    float e[8];
    e[0] = a0.x + d2 * g0.x + b1[0];
    e[1] = a0.y + d2 * g0.y + b1[1];
    e[2] = a0.z + d2 * g0.z + b1[2];
    e[3] = a0.w + d2 * g0.w + b1[3];
    e[4] = a1.x + d2 * g1.x + b1[4];
    e[5] = a1.y + d2 * g1.y + b1[5];
    e[6] = a1.z + d2 * g1.z + b1[6];
    e[7] = a1.w + d2 * g1.w + b1[7];
    float4* xo = reinterpret_cast<float4*>(xemb + (size_t)i * 8);
    xo[0] = make_float4(e[0], e[1], e[2], e[3]);
    xo[1] = make_float4(e[4], e[5], e[6], e[7]);
    float s0 = 0.0f, s1 = 0.0f;
#pragma unroll
    for (int j = 0; j < 8; ++j) {
        float r = fmaxf(e[j], 0.0f);
        s0 += r * W2[j * 2 + 0];
        s1 += r * W2[j * 2 + 1];
    }
    *reinterpret_cast<float2*>(h2 + (size_t)i * 2) = make_float2(s0, s1);
}

__device__ __forceinline__ void agg2_edge(int r, int c, float w,
                                          const float* __restrict__ dinv,
                                          const float* __restrict__ h2,
                                          float* __restrict__ agg2) {
    float nrm = dinv[r] * w * dinv[c];
    float2 v = *reinterpret_cast<const float2*>(h2 + (size_t)r * 2);
    float* o = agg2 + (size_t)c * 2;
    atomAdd(o + 0, nrm * v.x);
    atomAdd(o + 1, nrm * v.y);
}

__global__ __launch_bounds__(256) void k_agg2(const void* __restrict__ ei,
                                              const float* __restrict__ ew,
                                              const int* __restrict__ flag,
                                              const float* __restrict__ dinv,
                                              const float* __restrict__ h2,
                                              float* __restrict__ agg2) {
    const int is64 = *flag;
    const int stride = gridDim.x * blockDim.x;
    const int nv = NE / 4;
    const float4* ewv = (const float4*)ew;
    for (int v = blockIdx.x * blockDim.x + threadIdx.x; v < nv; v += stride) {
        int r[4], c[4];
        load4(ei, is64, v, 0, r);
        load4(ei, is64, v, NE, c);
        float4 w = ewv[v];
        agg2_edge(r[0], c[0], w.x, dinv, h2, agg2);
        agg2_edge(r[1], c[1], w.y, dinv, h2, agg2);
        agg2_edge(r[2], c[2], w.z, dinv, h2, agg2);
        agg2_edge(r[3], c[3], w.w, dinv, h2, agg2);
    }
}

__global__ __launch_bounds__(256) void k_epi2(const float* __restrict__ agg2,
                                              const float* __restrict__ h2,
                                              const float* __restrict__ dinv,
                                              const float* __restrict__ b2,
                                              float* __restrict__ out) {
    int i = blockIdx.x * blockDim.x + threadIdx.x;
    if (i >= NN) return;
    float di = dinv[i];
    float d2 = di * di;
    float2 a = *reinterpret_cast<const float2*>(agg2 + (size_t)i * 2);
    float2 h = *reinterpret_cast<const float2*>(h2 + (size_t)i * 2);
    *reinterpret_cast<float2*>(out + (size_t)i * 2) =
        make_float2(a.x + d2 * h.x + b2[0], a.y + d2 * h.y + b2[1]);
}

// ---------- host ----------

extern "C" void kernel_launch(void* const* d_in, const int* in_sizes, int n_in,
                              void* d_out, int out_size, void* d_ws, size_t ws_size,
                              hipStream_t stream) {
    const float* x  = (const float*)d_in[0];
    const void*  ei = d_in[1];                 // int32 confirmed (round-5 FETCH); detect = insurance
    const float* ew = (const float*)d_in[2];
    const float* W1 = (const float*)d_in[3];
    const float* b1 = (const float*)d_in[4];
    const float* W2 = (const float*)d_in[5];
    const float* b2 = (const float*)d_in[6];

    float* out  = (float*)d_out;               // [NN*2] then [NN*8] x_emb
    float* xemb = out + (size_t)NN * 2;

    const int NB = (NN + 255) / 256;

    // fast-path ws layout (~87 MB; round-8 proved >=104 MB available)
    size_t p = 0;
    size_t o_buckets = p; p += (size_t)GROUPS * CAP * 8;              // 56.0 MB
    size_t o_g1   = p; p += (size_t)GROUPS * KCH * GSIZE * 8 * 4;     // 19.2 MB
    size_t o_g2   = p; p += (size_t)GROUPS * KCH * GSIZE * 2 * 4;     //  4.8 MB
    size_t o_deg  = p; p += (size_t)GROUPS * KCH * GSIZE * 4;         //  2.4 MB
    size_t o_h1   = p; p += (size_t)NN * 8 * 4;                       //  3.2 MB
    size_t o_h2   = p; p += (size_t)NN * 2 * 4;                       //  0.8 MB
    size_t o_dinv = p; p += (size_t)NN * 4;                           //  0.4 MB
    size_t o_cur  = p; p += GROUPS * 4;
    size_t o_flag = p; p += 16;
    const size_t need = p;

    char* ws = (char*)d_ws;

    if (ws_size >= need) {
        unsigned long long* buckets = (unsigned long long*)(ws + o_buckets);
        float* g1part  = (float*)(ws + o_g1);
        float* g2part  = (float*)(ws + o_g2);
        float* degpart = (float*)(ws + o_deg);
        float* h1s     = (float*)(ws + o_h1);
        float* h2s     = (float*)(ws + o_h2);
        float* dinv    = (float*)(ws + o_dinv);
        unsigned* cursors = (unsigned*)(ws + o_cur);
        int* flag      = (int*)(ws + o_flag);

        hipMemsetAsync(cursors, 0, GROUPS * 4, stream);  // only accumulator needing zeros

        k_detect <<<1, 1, 0, stream>>>((const int*)ei, flag);
        k_bucket <<<NBB, 256, 0, stream>>>(ei, ew, flag, cursors, buckets);
        k_deg    <<<GROUPS * KCH, 512, 0, stream>>>(cursors, buckets, degpart);
        k_node1m <<<NB, 256, 0, stream>>>(x, W1, degpart, dinv, h1s);
        k_gather1<<<GROUPS * KCH, 512, 0, stream>>>(cursors, buckets, h1s, g1part);
        k_epi1m  <<<NB, 256, 0, stream>>>(g1part, h1s, dinv, W2, b1, xemb, h2s);
        k_gather2<<<GROUPS * KCH, 512, 0, stream>>>(cursors, buckets, h2s, g2part);
        k_epi2m  <<<NB, 256, 0, stream>>>(g2part, h2s, dinv, b2, out);
    } else {
        // ---- FALLBACK: round-5 passing path (atomic scatter) ----
        float* deg  = (float*)d_ws;                // NN
        float* agg1 = deg + NN;                    // NN*8
        float* agg2 = agg1 + (size_t)NN * 8;       // NN*2
        float* dinv = agg2 + (size_t)NN * 2;       // NN
        float* h1   = dinv + NN;                   // NN*8
        float* h2   = h1 + (size_t)NN * 8;         // NN*2
        int*   flag = (int*)(h2 + (size_t)NN * 2); // 1

        hipMemsetAsync(deg, 0, (size_t)NN * (1 + 8 + 2) * sizeof(float), stream);

        const int EB = 2048;
        k_detect<<<1, 1, 0, stream>>>((const int*)ei, flag);
        k_prep <<<EB, 256, 0, stream>>>(ei, ew, flag, deg);
        k_node1<<<NB, 256, 0, stream>>>(x, W1, deg, dinv, h1);
        k_agg1 <<<EB, 256, 0, stream>>>(ei, ew, flag, dinv, h1, agg1);
        k_epi1 <<<NB, 256, 0, stream>>>(agg1, h1, dinv, W2, b1, xemb, h2);
        k_agg2 <<<EB, 256, 0, stream>>>(ei, ew, flag, dinv, h2, agg2);
        k_epi2 <<<NB, 256, 0, stream>>>(agg2, h2, dinv, b2, out);
    }
}